// Round 1
// baseline (1347.686 us; speedup 1.0000x reference)
//
#include <hip/hip_runtime.h>

#define D_FEAT 128

// Kernel 1: out[v,d] = (1+eps) * h[v,d] * norm[v]^2   (full overwrite of d_out)
__global__ void gin_init(const float* __restrict__ h,
                         const float* __restrict__ norm,
                         const float* __restrict__ eps,
                         float* __restrict__ out,
                         int n_nodes) {
    int i = blockIdx.x * blockDim.x + threadIdx.x;   // in float4 units
    int total = n_nodes * (D_FEAT / 4);
    if (i >= total) return;
    int node = i / (D_FEAT / 4);
    float nm = norm[node];
    float scale = (1.0f + eps[0]) * nm * nm;
    const float4* h4 = reinterpret_cast<const float4*>(h);
    float4* o4 = reinterpret_cast<float4*>(out);
    float4 v = h4[i];
    v.x *= scale; v.y *= scale; v.z *= scale; v.w *= scale;
    o4[i] = v;
}

// Kernel 2: for each edge (s,d): out[d,:] += h[s,:] * norm[s] * norm[d]
// 32 lanes per edge, float4 per lane (32*4 = 128 features).
__global__ void gin_edge(const float* __restrict__ h,
                         const float* __restrict__ norm,
                         const int* __restrict__ src,
                         const int* __restrict__ dst,
                         float* __restrict__ out,
                         int n_edges) {
    long long t = (long long)blockIdx.x * blockDim.x + threadIdx.x;
    int e    = (int)(t >> 5);
    int lane = (int)(t & 31);
    if (e >= n_edges) return;
    int s = src[e];
    int d = dst[e];
    float coef = norm[s] * norm[d];
    const float4* hs = reinterpret_cast<const float4*>(h + (long long)s * D_FEAT);
    float4 v = hs[lane];
    float* od = out + (long long)d * D_FEAT + lane * 4;
    atomicAdd(od + 0, v.x * coef);
    atomicAdd(od + 1, v.y * coef);
    atomicAdd(od + 2, v.z * coef);
    atomicAdd(od + 3, v.w * coef);
}

extern "C" void kernel_launch(void* const* d_in, const int* in_sizes, int n_in,
                              void* d_out, int out_size, void* d_ws, size_t ws_size,
                              hipStream_t stream) {
    const float* h    = (const float*)d_in[0];
    const float* norm = (const float*)d_in[1];
    const float* eps  = (const float*)d_in[2];
    const int*   src  = (const int*)d_in[3];
    const int*   dst  = (const int*)d_in[4];
    float* out = (float*)d_out;

    int n_nodes = in_sizes[1];          // norm is [N,1] -> N elements
    int n_edges = in_sizes[3];          // src is [E]

    // Kernel 1: init/overwrite out
    int init_threads = n_nodes * (D_FEAT / 4);
    int init_blocks  = (init_threads + 255) / 256;
    gin_init<<<init_blocks, 256, 0, stream>>>(h, norm, eps, out, n_nodes);

    // Kernel 2: edge scatter-add
    long long edge_threads = (long long)n_edges * 32;
    int edge_blocks = (int)((edge_threads + 255) / 256);
    gin_edge<<<edge_blocks, 256, 0, stream>>>(h, norm, src, dst, out, n_edges);
}

// Round 2
// 273.537 us; speedup vs baseline: 4.9269x; 4.9269x over previous
//
#include <hip/hip_runtime.h>

#define D_FEAT 128

// ---------- CSR-build path ----------

__global__ void deg_count(const int* __restrict__ dst, int* __restrict__ counts,
                          int n_edges) {
    int i = blockIdx.x * blockDim.x + threadIdx.x;
    if (i < n_edges) atomicAdd(&counts[dst[i]], 1);
}

// single-block exclusive scan over counts[0..n-1] -> offs[0..n], cursor copy
__global__ void scan_counts(const int* __restrict__ counts, int* __restrict__ offs,
                            int* __restrict__ cursor, int n) {
    __shared__ int buf[1024];
    __shared__ int carry_s;
    int tid = threadIdx.x;
    if (tid == 0) carry_s = 0;
    __syncthreads();
    for (int base = 0; base < n; base += 1024) {
        int i = base + tid;
        int v = (i < n) ? counts[i] : 0;
        buf[tid] = v;
        __syncthreads();
        for (int off = 1; off < 1024; off <<= 1) {
            int t = (tid >= off) ? buf[tid - off] : 0;
            __syncthreads();
            buf[tid] += t;
            __syncthreads();
        }
        int incl = buf[tid];
        int carry = carry_s;
        if (i < n) {
            int ex = carry + incl - v;
            offs[i] = ex;
            cursor[i] = ex;
        }
        __syncthreads();
        if (tid == 1023) carry_s = carry + buf[1023];
        __syncthreads();
    }
    if (tid == 0) offs[n] = carry_s;
}

__global__ void scatter_csr(const int* __restrict__ src, const int* __restrict__ dst,
                            int* __restrict__ cursor, int* __restrict__ csr_src,
                            int n_edges) {
    int i = blockIdx.x * blockDim.x + threadIdx.x;
    if (i < n_edges) {
        int p = atomicAdd(&cursor[dst[i]], 1);
        csr_src[p] = src[i];
    }
}

// one wave (64 lanes) per dst node; float2 per lane covers D=128.
// out[v] = (1+eps)*h[v]*norm[v]^2 + norm[v] * sum_s h[s]*norm[s]
__global__ void gather_fused(const float* __restrict__ h,
                             const float* __restrict__ norm,
                             const float* __restrict__ eps,
                             const int* __restrict__ offs,
                             const int* __restrict__ csr_src,
                             float* __restrict__ out,
                             int n_nodes) {
    int node = blockIdx.x * 4 + (threadIdx.x >> 6);
    int lane = threadIdx.x & 63;
    if (node >= n_nodes) return;
    int beg = offs[node];
    int end = offs[node + 1];
    float accx = 0.0f, accy = 0.0f;
    for (int i = beg; i < end; ++i) {
        int s = csr_src[i];
        float ns = norm[s];
        float2 v = *reinterpret_cast<const float2*>(h + (long long)s * D_FEAT + lane * 2);
        accx += v.x * ns;
        accy += v.y * ns;
    }
    float nd = norm[node];
    float e1 = 1.0f + eps[0];
    float2 hv = *reinterpret_cast<const float2*>(h + (long long)node * D_FEAT + lane * 2);
    float2 o;
    o.x = (e1 * hv.x * nd + accx) * nd;
    o.y = (e1 * hv.y * nd + accy) * nd;
    *reinterpret_cast<float2*>(out + (long long)node * D_FEAT + lane * 2) = o;
}

// ---------- fallback (atomic scatter) ----------

__global__ void gin_init(const float* __restrict__ h, const float* __restrict__ norm,
                         const float* __restrict__ eps, float* __restrict__ out,
                         int n_nodes) {
    int i = blockIdx.x * blockDim.x + threadIdx.x;
    int total = n_nodes * (D_FEAT / 4);
    if (i >= total) return;
    int node = i / (D_FEAT / 4);
    float nm = norm[node];
    float scale = (1.0f + eps[0]) * nm * nm;
    const float4* h4 = reinterpret_cast<const float4*>(h);
    float4* o4 = reinterpret_cast<float4*>(out);
    float4 v = h4[i];
    v.x *= scale; v.y *= scale; v.z *= scale; v.w *= scale;
    o4[i] = v;
}

__global__ void gin_edge(const float* __restrict__ h, const float* __restrict__ norm,
                         const int* __restrict__ src, const int* __restrict__ dst,
                         float* __restrict__ out, int n_edges) {
    long long t = (long long)blockIdx.x * blockDim.x + threadIdx.x;
    int e = (int)(t >> 5);
    int lane = (int)(t & 31);
    if (e >= n_edges) return;
    int s = src[e], d = dst[e];
    float coef = norm[s] * norm[d];
    const float4* hs = reinterpret_cast<const float4*>(h + (long long)s * D_FEAT);
    float4 v = hs[lane];
    float* od = out + (long long)d * D_FEAT + lane * 4;
    atomicAdd(od + 0, v.x * coef);
    atomicAdd(od + 1, v.y * coef);
    atomicAdd(od + 2, v.z * coef);
    atomicAdd(od + 3, v.w * coef);
}

extern "C" void kernel_launch(void* const* d_in, const int* in_sizes, int n_in,
                              void* d_out, int out_size, void* d_ws, size_t ws_size,
                              hipStream_t stream) {
    const float* h    = (const float*)d_in[0];
    const float* norm = (const float*)d_in[1];
    const float* eps  = (const float*)d_in[2];
    const int*   src  = (const int*)d_in[3];
    const int*   dst  = (const int*)d_in[4];
    float* out = (float*)d_out;

    int n_nodes = in_sizes[1];
    int n_edges = in_sizes[3];

    size_t need = ((size_t)(n_nodes + 1) + (size_t)n_nodes + (size_t)n_edges) * 4;
    if (ws_size >= need) {
        int* offs    = (int*)d_ws;                 // n_nodes+1
        int* cursor  = offs + (n_nodes + 1);       // n_nodes (also used as counts)
        int* csr_src = cursor + n_nodes;           // n_edges

        hipMemsetAsync(cursor, 0, (size_t)n_nodes * 4, stream);

        int eb = (n_edges + 255) / 256;
        deg_count<<<eb, 256, 0, stream>>>(dst, cursor, n_edges);
        scan_counts<<<1, 1024, 0, stream>>>(cursor, offs, cursor, n_nodes);
        // note: scan_counts reads counts (=cursor) and rewrites cursor in place;
        // safe because each index i is read before written by the same thread.
        scatter_csr<<<eb, 256, 0, stream>>>(src, dst, cursor, csr_src, n_edges);

        int gb = (n_nodes + 3) / 4;
        gather_fused<<<gb, 256, 0, stream>>>(h, norm, eps, offs, csr_src, out, n_nodes);
    } else {
        int init_threads = n_nodes * (D_FEAT / 4);
        gin_init<<<(init_threads + 255) / 256, 256, 0, stream>>>(h, norm, eps, out, n_nodes);
        long long et = (long long)n_edges * 32;
        gin_edge<<<(int)((et + 255) / 256), 256, 0, stream>>>(h, norm, src, dst, out, n_edges);
    }
}

// Round 3
// 162.063 us; speedup vs baseline: 8.3158x; 1.6878x over previous
//
#include <hip/hip_runtime.h>

#define D_FEAT 128

// ---------- CSR-build path ----------

__global__ void deg_count(const int* __restrict__ dst, int* __restrict__ counts,
                          int n_edges) {
    int i = blockIdx.x * blockDim.x + threadIdx.x;
    if (i < n_edges) atomicAdd(&counts[dst[i]], 1);
}

// hierarchical scan, stage 1: per-block (1024 elems) local exclusive scan
__global__ void scan_local(const int* __restrict__ counts, int* __restrict__ offs,
                           int* __restrict__ blocksums, int n) {
    int tid = threadIdx.x;
    int base = blockIdx.x * 1024 + tid * 4;
    int v0 = (base + 0 < n) ? counts[base + 0] : 0;
    int v1 = (base + 1 < n) ? counts[base + 1] : 0;
    int v2 = (base + 2 < n) ? counts[base + 2] : 0;
    int v3 = (base + 3 < n) ? counts[base + 3] : 0;
    int tsum = v0 + v1 + v2 + v3;
    __shared__ int smem[256];
    smem[tid] = tsum;
    __syncthreads();
    for (int off = 1; off < 256; off <<= 1) {
        int t = (tid >= off) ? smem[tid - off] : 0;
        __syncthreads();
        smem[tid] += t;
        __syncthreads();
    }
    int ex = smem[tid] - tsum;
    if (base + 0 < n) offs[base + 0] = ex;
    if (base + 1 < n) offs[base + 1] = ex + v0;
    if (base + 2 < n) offs[base + 2] = ex + v0 + v1;
    if (base + 3 < n) offs[base + 3] = ex + v0 + v1 + v2;
    if (tid == 255) blocksums[blockIdx.x] = smem[255];
}

// stage 2: exclusive-scan the block sums in place (nb is small, ~49)
__global__ void scan_blocksums(int* __restrict__ blocksums, int* __restrict__ offs,
                               int nb, int n) {
    __shared__ int smem[256];
    __shared__ int carry_s;
    int tid = threadIdx.x;
    if (tid == 0) carry_s = 0;
    __syncthreads();
    for (int basei = 0; basei < nb; basei += 256) {
        int i = basei + tid;
        int v = (i < nb) ? blocksums[i] : 0;
        smem[tid] = v;
        __syncthreads();
        for (int off = 1; off < 256; off <<= 1) {
            int t = (tid >= off) ? smem[tid - off] : 0;
            __syncthreads();
            smem[tid] += t;
            __syncthreads();
        }
        int carry = carry_s;
        if (i < nb) blocksums[i] = carry + smem[tid] - v;  // exclusive
        __syncthreads();
        if (tid == 255) carry_s = carry + smem[255];
        __syncthreads();
    }
    if (tid == 0) offs[n] = carry_s;
}

// stage 3: add block offsets; produce final offs + cursor copy
__global__ void add_back(int* __restrict__ offs, int* __restrict__ cursor,
                         const int* __restrict__ blocksums, int n) {
    int i = blockIdx.x * 256 + threadIdx.x;
    if (i < n) {
        int v = offs[i] + blocksums[i >> 10];
        offs[i] = v;
        cursor[i] = v;
    }
}

__global__ void scatter_csr(const int* __restrict__ src, const int* __restrict__ dst,
                            int* __restrict__ cursor, int* __restrict__ csr_src,
                            int n_edges) {
    int i = blockIdx.x * blockDim.x + threadIdx.x;
    if (i < n_edges) {
        int p = atomicAdd(&cursor[dst[i]], 1);
        csr_src[p] = src[i];
    }
}

// one wave (64 lanes) per dst node; float2 per lane covers D=128.
// inner loop unrolled x4 for memory-level parallelism.
__global__ void gather_fused(const float* __restrict__ h,
                             const float* __restrict__ norm,
                             const float* __restrict__ eps,
                             const int* __restrict__ offs,
                             const int* __restrict__ csr_src,
                             float* __restrict__ out,
                             int n_nodes) {
    int node = blockIdx.x * 4 + (threadIdx.x >> 6);
    int lane = threadIdx.x & 63;
    if (node >= n_nodes) return;
    int beg = offs[node];
    int end = offs[node + 1];
    float accx = 0.0f, accy = 0.0f;
    int i = beg;
    for (; i + 3 < end; i += 4) {
        int s0 = csr_src[i + 0];
        int s1 = csr_src[i + 1];
        int s2 = csr_src[i + 2];
        int s3 = csr_src[i + 3];
        float n0 = norm[s0], n1 = norm[s1], n2 = norm[s2], n3 = norm[s3];
        float2 v0 = *reinterpret_cast<const float2*>(h + (long long)s0 * D_FEAT + lane * 2);
        float2 v1 = *reinterpret_cast<const float2*>(h + (long long)s1 * D_FEAT + lane * 2);
        float2 v2 = *reinterpret_cast<const float2*>(h + (long long)s2 * D_FEAT + lane * 2);
        float2 v3 = *reinterpret_cast<const float2*>(h + (long long)s3 * D_FEAT + lane * 2);
        accx += v0.x * n0 + v1.x * n1 + v2.x * n2 + v3.x * n3;
        accy += v0.y * n0 + v1.y * n1 + v2.y * n2 + v3.y * n3;
    }
    for (; i < end; ++i) {
        int s = csr_src[i];
        float ns = norm[s];
        float2 v = *reinterpret_cast<const float2*>(h + (long long)s * D_FEAT + lane * 2);
        accx += v.x * ns;
        accy += v.y * ns;
    }
    float nd = norm[node];
    float e1 = 1.0f + eps[0];
    float2 hv = *reinterpret_cast<const float2*>(h + (long long)node * D_FEAT + lane * 2);
    float2 o;
    o.x = (e1 * hv.x * nd + accx) * nd;
    o.y = (e1 * hv.y * nd + accy) * nd;
    *reinterpret_cast<float2*>(out + (long long)node * D_FEAT + lane * 2) = o;
}

// ---------- fallback (atomic scatter) ----------

__global__ void gin_init(const float* __restrict__ h, const float* __restrict__ norm,
                         const float* __restrict__ eps, float* __restrict__ out,
                         int n_nodes) {
    int i = blockIdx.x * blockDim.x + threadIdx.x;
    int total = n_nodes * (D_FEAT / 4);
    if (i >= total) return;
    int node = i / (D_FEAT / 4);
    float nm = norm[node];
    float scale = (1.0f + eps[0]) * nm * nm;
    const float4* h4 = reinterpret_cast<const float4*>(h);
    float4* o4 = reinterpret_cast<float4*>(out);
    float4 v = h4[i];
    v.x *= scale; v.y *= scale; v.z *= scale; v.w *= scale;
    o4[i] = v;
}

__global__ void gin_edge(const float* __restrict__ h, const float* __restrict__ norm,
                         const int* __restrict__ src, const int* __restrict__ dst,
                         float* __restrict__ out, int n_edges) {
    long long t = (long long)blockIdx.x * blockDim.x + threadIdx.x;
    int e = (int)(t >> 5);
    int lane = (int)(t & 31);
    if (e >= n_edges) return;
    int s = src[e], d = dst[e];
    float coef = norm[s] * norm[d];
    const float4* hs = reinterpret_cast<const float4*>(h + (long long)s * D_FEAT);
    float4 v = hs[lane];
    float* od = out + (long long)d * D_FEAT + lane * 4;
    atomicAdd(od + 0, v.x * coef);
    atomicAdd(od + 1, v.y * coef);
    atomicAdd(od + 2, v.z * coef);
    atomicAdd(od + 3, v.w * coef);
}

extern "C" void kernel_launch(void* const* d_in, const int* in_sizes, int n_in,
                              void* d_out, int out_size, void* d_ws, size_t ws_size,
                              hipStream_t stream) {
    const float* h    = (const float*)d_in[0];
    const float* norm = (const float*)d_in[1];
    const float* eps  = (const float*)d_in[2];
    const int*   src  = (const int*)d_in[3];
    const int*   dst  = (const int*)d_in[4];
    float* out = (float*)d_out;

    int n_nodes = in_sizes[1];
    int n_edges = in_sizes[3];
    int nb = (n_nodes + 1023) / 1024;

    size_t need = ((size_t)(n_nodes + 1) + (size_t)n_nodes + (size_t)n_edges
                   + (size_t)nb) * 4;
    if (ws_size >= need) {
        int* offs      = (int*)d_ws;               // n_nodes+1
        int* cursor    = offs + (n_nodes + 1);     // n_nodes (also counts)
        int* csr_src   = cursor + n_nodes;         // n_edges
        int* blocksums = csr_src + n_edges;        // nb

        hipMemsetAsync(cursor, 0, (size_t)n_nodes * 4, stream);

        int eb = (n_edges + 255) / 256;
        deg_count<<<eb, 256, 0, stream>>>(dst, cursor, n_edges);
        scan_local<<<nb, 256, 0, stream>>>(cursor, offs, blocksums, n_nodes);
        scan_blocksums<<<1, 256, 0, stream>>>(blocksums, offs, nb, n_nodes);
        add_back<<<(n_nodes + 255) / 256, 256, 0, stream>>>(offs, cursor, blocksums, n_nodes);
        scatter_csr<<<eb, 256, 0, stream>>>(src, dst, cursor, csr_src, n_edges);

        int gb = (n_nodes + 3) / 4;
        gather_fused<<<gb, 256, 0, stream>>>(h, norm, eps, offs, csr_src, out, n_nodes);
    } else {
        int init_threads = n_nodes * (D_FEAT / 4);
        gin_init<<<(init_threads + 255) / 256, 256, 0, stream>>>(h, norm, eps, out, n_nodes);
        long long et = (long long)n_edges * 32;
        gin_edge<<<(int)((et + 255) / 256), 256, 0, stream>>>(h, norm, src, dst, out, n_edges);
    }
}